// Round 6
// baseline (364.586 us; speedup 1.0000x reference)
//
#include <hip/hip_runtime.h>

#define N_NODES 50000
#define N_EDGES 800000

#define BSHIFT 6
#define BVALS 64                       // nodes per bucket
#define NBUK ((N_NODES + BVALS - 1) / BVALS + 1)   // 782 (covers node ids up to 50047)
#define BCAP 2048                      // max edges per bucket (mean ~1023, 16 sigma)

// ---------------- bf16 helpers (tables stored bf16, math in fp32) ----------------

__device__ __forceinline__ float bf2f(unsigned short u) {
    return __uint_as_float(((unsigned)u) << 16);
}
__device__ __forceinline__ unsigned short f2bf(float f) {
    unsigned u = __float_as_uint(f);
    u += 0x7FFFu + ((u >> 16) & 1u);   // round-to-nearest-even
    return (unsigned short)(u >> 16);
}
__device__ __forceinline__ void stv(float* p, float v) { *p = v; }
__device__ __forceinline__ void stv(unsigned short* p, float v) { *p = f2bf(v); }

// ---------------- CSR build via bucketed counting sort ----------------
// pass 1: partition edges into buckets of 64 dst-nodes; packed (dstlow<<16)|src.

__global__ __launch_bounds__(256) void partition_kernel(
        const int* __restrict__ ei, int* __restrict__ bcnt,
        int* __restrict__ bpk, int E) {
    int e = blockIdx.x * 256 + threadIdx.x;
    if (e >= E) return;
    int s = ei[e];
    int d = ei[E + e];
    int b = d >> BSHIFT;
    int pos = atomicAdd(&bcnt[b], 1);
    if (pos < BCAP) bpk[b * BCAP + pos] = ((d & (BVALS - 1)) << 16) | s;
}

// pass 2: exclusive scan of bucket counts (NBUK=782 <= 1024, single block).

__global__ __launch_bounds__(1024) void scan_bcnt_kernel(
        const int* __restrict__ bcnt, int* __restrict__ bofs, int NB) {
    __shared__ int lds[1024];
    int tid = threadIdx.x;
    int v = (tid < NB) ? bcnt[tid] : 0;
    lds[tid] = v;
    __syncthreads();
    for (int off = 1; off < 1024; off <<= 1) {
        int u = (tid >= off) ? lds[tid - off] : 0;
        __syncthreads();
        lds[tid] += u;
        __syncthreads();
    }
    if (tid < NB) bofs[tid] = lds[tid] - v;   // exclusive
}

// pass 3: per-bucket counting sort in LDS; writes rowptr (64 nodes) + elist segment.

__global__ __launch_bounds__(256) void bucket_sort_kernel(
        const int* __restrict__ bpk, const int* __restrict__ bcnt,
        const int* __restrict__ bofs,
        int* __restrict__ rowptr, int* __restrict__ elist, int N) {
    __shared__ int pk[BCAP];
    __shared__ int sc[BVALS];
    __shared__ int ex[BVALS];
    __shared__ int cur[BVALS];
    int b = blockIdx.x;
    int t = threadIdx.x;
    int nb = min(bcnt[b], BCAP);
    int base = bofs[b];

    if (t < BVALS) sc[t] = 0;
    __syncthreads();
    for (int i = t; i < nb; i += 256) {
        int v = bpk[b * BCAP + i];
        pk[i] = v;
        atomicAdd(&sc[v >> 16], 1);
    }
    __syncthreads();
    // exclusive scan of the 64-bin histogram (Hillis-Steele in LDS)
    int hv = (t < BVALS) ? sc[t] : 0;
#pragma unroll
    for (int off = 1; off < BVALS; off <<= 1) {
        int u = (t < BVALS && t >= off) ? sc[t - off] : 0;
        __syncthreads();
        if (t < BVALS) sc[t] += u;
        __syncthreads();
    }
    if (t < BVALS) {
        int e0 = sc[t] - hv;
        ex[t] = e0;
        cur[t] = e0;
        int n = b * BVALS + t;
        if (n <= N) rowptr[n] = base + e0;   // covers rowptr[N]=E via last bucket
    }
    __syncthreads();
    for (int i = t; i < nb; i += 256) {
        int v = pk[i];
        int pos = atomicAdd(&cur[v >> 16], 1);
        elist[base + pos] = v & 0xFFFF;      // src (fits in 16 bits)
    }
}

// ---------------- fused dual GEMM: C0 = A@W0, C1 = A@W1 ----------------
// A [N,K] fp32, W [K,64] fp32. Outputs templated: fp32 or bf16 (gather tables).

template<int K, typename T0, typename T1>
__global__ __launch_bounds__(256) void gemm_dual_kernel(
        const float* __restrict__ A,
        const float* __restrict__ W0, const float* __restrict__ W1,
        T0* __restrict__ C0, T1* __restrict__ C1, int N) {
    __shared__ float a_lds[32 * K];
    int t = threadIdx.x;
    int n0 = blockIdx.x * 32;

    const int total4 = 32 * K / 4;
    for (int idx = t; idx < total4; idx += 256) {
        int f = idx * 4;
        int r = f / K, c = f % K;
        float4 v = make_float4(0.f, 0.f, 0.f, 0.f);
        if (n0 + r < N) v = *(const float4*)&A[(size_t)(n0 + r) * K + c];
        *(float4*)&a_lds[f] = v;
    }
    __syncthreads();

    int o = t & 63;
    int g = t >> 6;
    float acc0[8], acc1[8];
#pragma unroll
    for (int i = 0; i < 8; ++i) { acc0[i] = 0.f; acc1[i] = 0.f; }

#pragma unroll 2
    for (int k4 = 0; k4 < K; k4 += 4) {
        float w00 = W0[(k4 + 0) * 64 + o];
        float w01 = W0[(k4 + 1) * 64 + o];
        float w02 = W0[(k4 + 2) * 64 + o];
        float w03 = W0[(k4 + 3) * 64 + o];
        float w10 = W1[(k4 + 0) * 64 + o];
        float w11 = W1[(k4 + 1) * 64 + o];
        float w12 = W1[(k4 + 2) * 64 + o];
        float w13 = W1[(k4 + 3) * 64 + o];
#pragma unroll
        for (int i = 0; i < 8; ++i) {
            float4 a = *(const float4*)&a_lds[(g * 8 + i) * K + k4];
            acc0[i] = fmaf(a.x, w00, acc0[i]);
            acc0[i] = fmaf(a.y, w01, acc0[i]);
            acc0[i] = fmaf(a.z, w02, acc0[i]);
            acc0[i] = fmaf(a.w, w03, acc0[i]);
            acc1[i] = fmaf(a.x, w10, acc1[i]);
            acc1[i] = fmaf(a.y, w11, acc1[i]);
            acc1[i] = fmaf(a.z, w12, acc1[i]);
            acc1[i] = fmaf(a.w, w13, acc1[i]);
        }
    }
#pragma unroll
    for (int i = 0; i < 8; ++i) {
        int n = n0 + g * 8 + i;
        if (n < N) {
            stv(&C0[(size_t)n * 64 + o], acc0[i]);
            stv(&C1[(size_t)n * 64 + o], acc1[i]);
        }
    }
}

// ---------------- mean-aggregate + bias + residual + relu ----------------
// H[n] = relu( mean_{s in in(n)} P[s] + bias + R[n] );  P is a bf16 table.
// 16 lanes per node: one wave instruction reads a full 128B row, coalesced.

__global__ __launch_bounds__(256) void agg_relu_kernel(
        const unsigned short* __restrict__ P, const float* __restrict__ R,
        const float* __restrict__ bias,
        const int* __restrict__ rowptr, const int* __restrict__ elist,
        float* __restrict__ H, int N) {
    int t = threadIdx.x;
    int n = blockIdx.x * 16 + (t >> 4);
    int l = t & 15;
    if (n >= N) return;
    int r0 = rowptr[n], r1 = rowptr[n + 1];
    float4 a0 = make_float4(0.f, 0.f, 0.f, 0.f);
    float4 a1 = make_float4(0.f, 0.f, 0.f, 0.f);
    int p = r0;
    for (; p + 2 <= r1; p += 2) {
        int sA = elist[p];
        int sB = elist[p + 1];
        ushort4 v0 = *(const ushort4*)&P[(size_t)sA * 64 + l * 4];
        ushort4 v1 = *(const ushort4*)&P[(size_t)sB * 64 + l * 4];
        a0.x += bf2f(v0.x); a0.y += bf2f(v0.y); a0.z += bf2f(v0.z); a0.w += bf2f(v0.w);
        a1.x += bf2f(v1.x); a1.y += bf2f(v1.y); a1.z += bf2f(v1.z); a1.w += bf2f(v1.w);
    }
    if (p < r1) {
        int sA = elist[p];
        ushort4 v0 = *(const ushort4*)&P[(size_t)sA * 64 + l * 4];
        a0.x += bf2f(v0.x); a0.y += bf2f(v0.y); a0.z += bf2f(v0.z); a0.w += bf2f(v0.w);
    }
    a0.x += a1.x; a0.y += a1.y; a0.z += a1.z; a0.w += a1.w;
    float inv = 1.0f / fmaxf((float)(r1 - r0), 1.0f);
    float4 b = *(const float4*)&bias[l * 4];
    float4 rr = *(const float4*)&R[(size_t)n * 64 + l * 4];
    float4 h;
    h.x = fmaxf(fmaf(a0.x, inv, b.x + rr.x), 0.f);
    h.y = fmaxf(fmaf(a0.y, inv, b.y + rr.y), 0.f);
    h.z = fmaxf(fmaf(a0.z, inv, b.z + rr.z), 0.f);
    h.w = fmaxf(fmaf(a0.w, inv, b.w + rr.w), 0.f);
    *(float4*)&H[(size_t)n * 64 + l * 4] = h;
}

// ---------------- edge output: out[e] = relu(Pa[src] + Pb[dst] + bm1) @ Wm2 + bm2 ----
// 16 lanes per edge (coalesced 128B bf16 row reads), 4 edges per thread,
// 16-wide shfl_xor reduction for the 64->2 projection.

__global__ __launch_bounds__(256) void edge_out_kernel(
        const unsigned short* __restrict__ Pa, const unsigned short* __restrict__ Pb,
        const int* __restrict__ ei,
        const float* __restrict__ bm1,
        const float* __restrict__ Wm2, const float* __restrict__ bm2,
        float* __restrict__ out, int E) {
    int t = threadIdx.x;
    int l = t & 15;
    int eg = t >> 4;
    int base = blockIdx.x * 64 + eg;

    float4 bb  = *(const float4*)&bm1[l * 4];
    float4 w01 = *(const float4*)&Wm2[l * 8];      // w[l4+0][0..1], w[l4+1][0..1]
    float4 w23 = *(const float4*)&Wm2[l * 8 + 4];  // w[l4+2][0..1], w[l4+3][0..1]
    float ob0 = bm2[0], ob1 = bm2[1];

#pragma unroll
    for (int it = 0; it < 4; ++it) {
        int e = base + it * 16;
        int s = ei[e];
        int d = ei[E + e];
        ushort4 ua = *(const ushort4*)&Pa[(size_t)s * 64 + l * 4];
        ushort4 ub = *(const ushort4*)&Pb[(size_t)d * 64 + l * 4];
        float h0 = fmaxf(bf2f(ua.x) + bf2f(ub.x) + bb.x, 0.f);
        float h1 = fmaxf(bf2f(ua.y) + bf2f(ub.y) + bb.y, 0.f);
        float h2 = fmaxf(bf2f(ua.z) + bf2f(ub.z) + bb.z, 0.f);
        float h3 = fmaxf(bf2f(ua.w) + bf2f(ub.w) + bb.w, 0.f);
        float s0 = h0 * w01.x + h1 * w01.z + h2 * w23.x + h3 * w23.z;
        float s1 = h0 * w01.y + h1 * w01.w + h2 * w23.y + h3 * w23.w;
#pragma unroll
        for (int off = 8; off >= 1; off >>= 1) {
            s0 += __shfl_xor(s0, off, 64);
            s1 += __shfl_xor(s1, off, 64);
        }
        if (l == 0) {
            *(float2*)&out[(size_t)e * 2] = make_float2(s0 + ob0, s1 + ob1);
        }
    }
}

// ---------------- launch ----------------

extern "C" void kernel_launch(void* const* d_in, const int* in_sizes, int n_in,
                              void* d_out, int out_size, void* d_ws, size_t ws_size,
                              hipStream_t stream) {
    const float* x   = (const float*)d_in[0];
    const int*   ei  = (const int*)d_in[1];
    const float* W1l = (const float*)d_in[2];
    const float* b1l = (const float*)d_in[3];
    const float* W1r = (const float*)d_in[4];
    const float* W2l = (const float*)d_in[5];
    const float* b2l = (const float*)d_in[6];
    const float* W2r = (const float*)d_in[7];
    const float* Wm1 = (const float*)d_in[8];
    const float* bm1 = (const float*)d_in[9];
    const float* Wm2 = (const float*)d_in[10];
    const float* bm2 = (const float*)d_in[11];
    float* out = (float*)d_out;

    const int N = N_NODES, E = N_EDGES;

    // B0: bf16 table (xl -> p2l -> Pa), B1: fp32 p1r/h1 then bf16 Pb, B2: fp32 p2r/h2
    float* B0 = (float*)d_ws;                    // 12.8 MB slot
    float* B1 = B0 + (size_t)N * 64;             // 12.8 MB slot
    float* B2 = B1 + (size_t)N * 64;             // 12.8 MB slot
    int* rowptr = (int*)(B2 + (size_t)N * 64);   // [N+1]
    int* elist  = rowptr + N + 1;                // [E]
    int* bcnt   = elist + E;                     // [NBUK]
    int* bofs   = bcnt + NBUK;                   // [NBUK]
    // bpk aliases the B2 slot: consumed by bucket_sort_kernel before conv2 writes B2.
    int* bpk    = (int*)B2;                      // [NBUK * BCAP] = 6.4 MB <= 12.8 MB

    unsigned short* B0h = (unsigned short*)B0;
    unsigned short* B1h = (unsigned short*)B1;

    hipMemsetAsync(bcnt, 0, sizeof(int) * NBUK, stream);

    // CSR build: partition -> scan -> per-bucket counting sort
    partition_kernel<<<(E + 255) / 256, 256, 0, stream>>>(ei, bcnt, bpk, E);
    scan_bcnt_kernel<<<1, 1024, 0, stream>>>(bcnt, bofs, NBUK);
    bucket_sort_kernel<<<NBUK, 256, 0, stream>>>(bpk, bcnt, bofs, rowptr, elist, N);

    // conv1: xl = x@W1l (B0, bf16), p1r = x@W1r (B1, fp32)
    gemm_dual_kernel<128><<<(N + 31) / 32, 256, 0, stream>>>(x, W1l, W1r, B0h, B1, N);
    // h1 = relu(mean(xl[src]) + b1l + p1r) -> B1 (fp32)
    agg_relu_kernel<<<(N + 15) / 16, 256, 0, stream>>>(B0h, B1, b1l, rowptr, elist, B1, N);

    // conv2: p2l = h1@W2l (B0, bf16), p2r = h1@W2r (B2, fp32)
    gemm_dual_kernel<64><<<(N + 31) / 32, 256, 0, stream>>>(B1, W2l, W2r, B0h, B2, N);
    // h2 = relu(mean(p2l[src]) + b2l + p2r) -> B2 (fp32)
    agg_relu_kernel<<<(N + 15) / 16, 256, 0, stream>>>(B0h, B2, b2l, rowptr, elist, B2, N);

    // edge-MLP first layer, per-node halves: Pa = h2@Wm1_top (B0, bf16), Pb = h2@Wm1_bot (B1, bf16)
    gemm_dual_kernel<64><<<(N + 31) / 32, 256, 0, stream>>>(B2, Wm1, Wm1 + 64 * 64, B0h, B1h, N);

    // per-edge: out = relu(Pa[src] + Pb[dst] + bm1) @ Wm2 + bm2
    edge_out_kernel<<<E / 64, 256, 0, stream>>>(B0h, B1h, ei, bm1, Wm2, bm2, out, E);
}